// Round 7
// baseline (811.150 us; speedup 1.0000x reference)
//
#include <hip/hip_runtime.h>
#include <hip/hip_bf16.h>

typedef __bf16 bf16x8 __attribute__((ext_vector_type(8)));
typedef float f32x4 __attribute__((ext_vector_type(4)));
static_assert(sizeof(bf16x8) == 16, "bf16x8 must be 16B");

constexpr int S = 2048, D = 128, HQ = 32, W = 1024;
constexpr float SCALE_L2E = 0.08838834764831845f * 1.4426950408889634f;

constexpr size_t O1 = (size_t)S * HQ * D;        // attn_weights offset
constexpr size_t O2 = O1 + (size_t)HQ * S * S;   // window offset
constexpr int TILE_BYTES = 64 * 256;             // 16 KB per tile image

__device__ __forceinline__ void gl_lds16(const void* g, void* l) {
    __builtin_amdgcn_global_load_lds(
        (const __attribute__((address_space(1))) void*)(unsigned long long)g,
        (__attribute__((address_space(3))) void*)(unsigned int)(unsigned long long)l,
        16, 0, 0);
}
__device__ __forceinline__ void st_nt4(float* p, f32x4 v) {
    __builtin_nontemporal_store(v, reinterpret_cast<f32x4*>(p));
}

// ---------------- prep: K,V -> bf16 pre-swizzled tile images in ws ----------------
__global__ __launch_bounds__(256)
void prep_kernel(const float* __restrict__ K, const float* __restrict__ V,
                 char* __restrict__ KbI, char* __restrict__ VtI)
{
    __shared__ __attribute__((aligned(16))) __bf16 Vs[128][72];
    const int b = blockIdx.x, hkv = b >> 5, kt = b & 31;
    const int tid = threadIdx.x;
    const float* Ks   = K + ((size_t)hkv * S + kt * 64) * D;
    const float* Vsrc = V + ((size_t)hkv * S + kt * 64) * D;
    char* Kimg = KbI + (size_t)(hkv * 32 + kt) * TILE_BYTES;
    char* Vimg = VtI + (size_t)(hkv * 32 + kt) * TILE_BYTES;

    #pragma unroll
    for (int i = 0; i < 4; ++i) {
        int idx = tid + i * 256;
        int r = idx >> 4, sl = idx & 15;
        float4 a = *reinterpret_cast<const float4*>(Ks + r * D + sl * 8);
        float4 c = *reinterpret_cast<const float4*>(Ks + r * D + sl * 8 + 4);
        bf16x8 f = {(__bf16)a.x, (__bf16)a.y, (__bf16)a.z, (__bf16)a.w,
                    (__bf16)c.x, (__bf16)c.y, (__bf16)c.z, (__bf16)c.w};
        *reinterpret_cast<bf16x8*>(Kimg + r * 256 + ((sl * 16) ^ ((r & 7) << 4))) = f;
    }
    #pragma unroll
    for (int i = 0; i < 8; ++i) {
        int idx = tid + i * 256;
        int r = idx >> 5, c = (idx & 31) * 4;
        float4 vv = *reinterpret_cast<const float4*>(Vsrc + r * D + c);
        Vs[c + 0][r] = (__bf16)vv.x; Vs[c + 1][r] = (__bf16)vv.y;
        Vs[c + 2][r] = (__bf16)vv.z; Vs[c + 3][r] = (__bf16)vv.w;
    }
    __syncthreads();
    #pragma unroll
    for (int i = 0; i < 4; ++i) {
        int idx = tid + i * 256;
        int d = idx >> 3, sl = idx & 7;
        bf16x8 v = *reinterpret_cast<const bf16x8*>(&Vs[d][sl * 8]);
        *reinterpret_cast<bf16x8*>(Vimg + d * 128 + ((sl * 16) ^ ((d & 7) << 4))) = v;
    }
}

// ------- main: 4-wave blocks, one 64-row q-tile, single-buffer LDS, 4 blocks/CU -------
__global__ __launch_bounds__(256, 4)
void attn_fused4(const float* __restrict__ Q, const char* __restrict__ KbI,
                 const char* __restrict__ VtI, float* __restrict__ out)
{
    __shared__ __attribute__((aligned(16))) char LDS_K[TILE_BYTES];   // 16 KB
    __shared__ __attribute__((aligned(16))) char LDS_V[TILE_BYTES];   // 16 KB
    __shared__ __attribute__((aligned(16))) char LDS_P[4][2048];      // 8 KB  -> 40 KB total

    const int bid = blockIdx.x;
    const int j   = bid >> 5;
    // per-CU resident set -> qt {16+x, 15-x, 31-x, x}: balanced iteration totals
    const int qt = (j < 8) ? (16 + j) : (j < 16) ? (23 - j) : (j < 24) ? (47 - j) : (j - 24);
    const int b5 = bid & 31;
    const int h  = (b5 & 7) * 4 + (b5 >> 3);   // hkv == bid%8 == XCD id (L2 locality)
    const int hkv = h >> 2;
    const int q0  = qt << 6;
    const int tid = threadIdx.x, wave = tid >> 6, lane = tid & 63;
    const int lo = lane & 15, hi = lane >> 4;
    const int qw0 = q0 + wave * 16;
    const bool winw = (qt >= 16);

    const char* Ktiles = KbI + (size_t)hkv * 32 * TILE_BYTES;
    const char* Vtiles = VtI + (size_t)hkv * 32 * TILE_BYTES;
    const float* Qh = Q + (size_t)h * S * D;

    // Q fragments (pre-scaled)
    bf16x8 qf[4];
    {
        const float* qs = Qh + (size_t)(qw0 + lo) * D + hi * 8;
        #pragma unroll
        for (int dc = 0; dc < 4; ++dc) {
            float4 a = *reinterpret_cast<const float4*>(qs + dc * 32);
            float4 b = *reinterpret_cast<const float4*>(qs + dc * 32 + 4);
            bf16x8 f;
            f[0] = (__bf16)(a.x * SCALE_L2E); f[1] = (__bf16)(a.y * SCALE_L2E);
            f[2] = (__bf16)(a.z * SCALE_L2E); f[3] = (__bf16)(a.w * SCALE_L2E);
            f[4] = (__bf16)(b.x * SCALE_L2E); f[5] = (__bf16)(b.y * SCALE_L2E);
            f[6] = (__bf16)(b.z * SCALE_L2E); f[7] = (__bf16)(b.w * SCALE_L2E);
            qf[dc] = f;
        }
    }

    // ================= phase A: row sums =================
    float lsum[4] = {0.f, 0.f, 0.f, 0.f};
    for (int kt = 0; kt <= qt; ++kt) {
        const char* src = Ktiles + (size_t)kt * TILE_BYTES;
        #pragma unroll
        for (int i = 0; i < 4; ++i)
            gl_lds16(src + (wave * 4 + i) * 1024 + lane * 16,
                     LDS_K + (wave * 4 + i) * 1024);
        __builtin_amdgcn_sched_barrier(0);
        asm volatile("s_waitcnt vmcnt(0)" ::: "memory");
        __builtin_amdgcn_s_barrier();
        __builtin_amdgcn_sched_barrier(0);
        #pragma unroll
        for (int cg = 0; cg < 4; ++cg) {
            f32x4 acc = {0.f, 0.f, 0.f, 0.f};
            const int row = cg * 16 + lo, swzr = (row & 7) << 4;
            #pragma unroll
            for (int dc = 0; dc < 4; ++dc) {
                bf16x8 kf = *reinterpret_cast<const bf16x8*>(
                    LDS_K + row * 256 + ((hi * 16 + dc * 64) ^ swzr));
                acc = __builtin_amdgcn_mfma_f32_16x16x32_bf16(qf[dc], kf, acc, 0, 0, 0);
            }
            const int k = (kt << 6) + cg * 16 + lo;
            #pragma unroll
            for (int r = 0; r < 4; ++r) {
                int q = qw0 + hi * 4 + r;
                lsum[r] += (k <= q) ? exp2f(acc[r]) : 0.f;
            }
        }
        // RACE FIX: raw s_barrier does NOT drain lgkm; a pending ds_read could
        // sample LDS after another wave's next-tile DMA lands. Drain LDS ops first.
        __builtin_amdgcn_sched_barrier(0);
        asm volatile("s_waitcnt lgkmcnt(0)" ::: "memory");
        __builtin_amdgcn_s_barrier();
        __builtin_amdgcn_sched_barrier(0);
    }
    float rcp_[4];
    #pragma unroll
    for (int r = 0; r < 4; ++r) {
        float v = lsum[r];
        v += __shfl_xor(v, 1); v += __shfl_xor(v, 2);
        v += __shfl_xor(v, 4); v += __shfl_xor(v, 8);
        rcp_[r] = 1.0f / v;
    }

    // ================= phase B =================
    f32x4 oacc[8];
    #pragma unroll
    for (int i = 0; i < 8; ++i) oacc[i] = (f32x4){0.f, 0.f, 0.f, 0.f};
    char* Ps = LDS_P[wave];

    for (int kt = 0; kt <= qt; ++kt) {
        const char* sk = Ktiles + (size_t)kt * TILE_BYTES;
        const char* sv = Vtiles + (size_t)kt * TILE_BYTES;
        #pragma unroll
        for (int i = 0; i < 4; ++i) {
            gl_lds16(sk + (wave * 4 + i) * 1024 + lane * 16, LDS_K + (wave * 4 + i) * 1024);
            gl_lds16(sv + (wave * 4 + i) * 1024 + lane * 16, LDS_V + (wave * 4 + i) * 1024);
        }
        __builtin_amdgcn_sched_barrier(0);
        asm volatile("s_waitcnt vmcnt(0)" ::: "memory");
        __builtin_amdgcn_s_barrier();
        __builtin_amdgcn_sched_barrier(0);

        const int kbase = kt << 6;

        // QK^T -> p -> per-wave P strip (bf16)
        #pragma unroll
        for (int cg = 0; cg < 4; ++cg) {
            f32x4 acc = {0.f, 0.f, 0.f, 0.f};
            const int row = cg * 16 + lo, swzr = (row & 7) << 4;
            #pragma unroll
            for (int dc = 0; dc < 4; ++dc) {
                bf16x8 kf = *reinterpret_cast<const bf16x8*>(
                    LDS_K + row * 256 + ((hi * 16 + dc * 64) ^ swzr));
                acc = __builtin_amdgcn_mfma_f32_16x16x32_bf16(qf[dc], kf, acc, 0, 0, 0);
            }
            const int k = kbase + cg * 16 + lo;
            #pragma unroll
            for (int r = 0; r < 4; ++r) {
                const int q = qw0 + hi * 4 + r;
                float pv = (k <= q) ? exp2f(acc[r]) * rcp_[r] : 0.f;
                const int prow = hi * 4 + r;
                *reinterpret_cast<__bf16*>(
                    Ps + prow * 128 + ((2 * (cg * 16 + lo)) ^ ((prow & 7) << 4))) = (__bf16)pv;
            }
        }

        // wide P (+window) stores from strip readback (non-temporal)
        {
            const int row = lane >> 2;
            const int q = qw0 + row;
            float* dstP = out + O1 + ((size_t)h * S + q) * S + kbase;
            #pragma unroll
            for (int t = 0; t < 2; ++t) {
                int boff = (((lane & 3) * 16 + t * 64) ^ ((row & 7) << 4));
                bf16x8 pv8 = *reinterpret_cast<const bf16x8*>(Ps + row * 128 + boff);
                f32x4 f0 = {(float)pv8[0], (float)pv8[1], (float)pv8[2], (float)pv8[3]};
                f32x4 f1 = {(float)pv8[4], (float)pv8[5], (float)pv8[6], (float)pv8[7]};
                int k0 = (lane & 3) * 8 + t * 32;
                st_nt4(dstP + k0, f0);
                st_nt4(dstP + k0 + 4, f1);
                if (winw) {
                    float* dstW = out + O2 + ((size_t)h * W + (q - W)) * S + kbase;
                    st_nt4(dstW + k0, f0);
                    st_nt4(dstW + k0 + 4, f1);
                }
            }
        }

        // PV accumulate
        #pragma unroll
        for (int kc = 0; kc < 2; ++kc) {
            const int cb = (kc * 64 + hi * 16) ^ ((lo & 7) << 4);
            bf16x8 pf = *reinterpret_cast<const bf16x8*>(Ps + lo * 128 + cb);
            #pragma unroll
            for (int dg = 0; dg < 8; ++dg) {
                bf16x8 vf = *reinterpret_cast<const bf16x8*>(LDS_V + (dg * 16 + lo) * 128 + cb);
                oacc[dg] = __builtin_amdgcn_mfma_f32_16x16x32_bf16(pf, vf, oacc[dg], 0, 0, 0);
            }
        }

        // RACE FIX (same as phase A): drain this wave's LDS ops before signaling.
        __builtin_amdgcn_sched_barrier(0);
        asm volatile("s_waitcnt lgkmcnt(0)" ::: "memory");
        __builtin_amdgcn_s_barrier();
        __builtin_amdgcn_sched_barrier(0);
    }

    // zero-fill masked tiles (non-temporal)
    {
        const int zr = lane >> 2;
        const int c0 = (lane & 3) * 16;
        const f32x4 z = {0.f, 0.f, 0.f, 0.f};
        const int q = qw0 + zr;
        for (int kt = qt + 1; kt < 32; ++kt) {
            float* dp = out + O1 + ((size_t)h * S + q) * S + kt * 64 + c0;
            #pragma unroll
            for (int jj = 0; jj < 4; ++jj) st_nt4(dp + jj * 4, z);
            if (winw) {
                float* dw = out + O2 + ((size_t)h * W + (q - W)) * S + kt * 64 + c0;
                #pragma unroll
                for (int jj = 0; jj < 4; ++jj) st_nt4(dw + jj * 4, z);
            }
        }
    }

    // attn_output (S, HQ, D)
    #pragma unroll
    for (int dg = 0; dg < 8; ++dg) {
        #pragma unroll
        for (int r = 0; r < 4; ++r) {
            const int q = qw0 + hi * 4 + r;
            __builtin_nontemporal_store(oacc[dg][r], out + ((size_t)q * HQ + h) * D + dg * 16 + lo);
        }
    }
}

extern "C" void kernel_launch(void* const* d_in, const int* in_sizes, int n_in,
                              void* d_out, int out_size, void* d_ws, size_t ws_size,
                              hipStream_t stream)
{
    const float* Q = (const float*)d_in[0];
    const float* K = (const float*)d_in[1];
    const float* V = (const float*)d_in[2];
    float* out = (float*)d_out;

    char* KbI = (char*)d_ws;                                   // 4 MB tile images
    char* VtI = (char*)d_ws + (size_t)4 * 1024 * 1024;         // 4 MB tile images

    hipLaunchKernelGGL(prep_kernel, dim3(256),  dim3(256), 0, stream, K, V, KbI, VtI);
    hipLaunchKernelGGL(attn_fused4, dim3(1024), dim3(256), 0, stream, Q, KbI, VtI, out);
}

// Round 8
// 300.636 us; speedup vs baseline: 2.6981x; 2.6981x over previous
//
#include <hip/hip_runtime.h>
#include <hip/hip_bf16.h>

typedef __bf16 bf16x8 __attribute__((ext_vector_type(8)));
typedef float f32x4 __attribute__((ext_vector_type(4)));
static_assert(sizeof(bf16x8) == 16, "bf16x8 must be 16B");

constexpr int S = 2048, D = 128, HQ = 32, W = 1024;
constexpr float SCALE_L2E = 0.08838834764831845f * 1.4426950408889634f;

constexpr size_t O1 = (size_t)S * HQ * D;        // attn_weights offset
constexpr size_t O2 = O1 + (size_t)HQ * S * S;   // window offset
constexpr int TILE_BYTES = 64 * 256;             // 16 KB per tile image

__device__ __forceinline__ void gl_lds16(const void* g, void* l) {
    __builtin_amdgcn_global_load_lds(
        (const __attribute__((address_space(1))) void*)(unsigned long long)g,
        (__attribute__((address_space(3))) void*)(unsigned int)(unsigned long long)l,
        16, 0, 0);
}
__device__ __forceinline__ void st4(float* p, f32x4 v) {
    *reinterpret_cast<f32x4*>(p) = v;   // regular store: completes at L2
}

// ---------------- prep: K,V -> bf16 pre-swizzled tile images in ws ----------------
__global__ __launch_bounds__(256)
void prep_kernel(const float* __restrict__ K, const float* __restrict__ V,
                 char* __restrict__ KbI, char* __restrict__ VtI)
{
    __shared__ __attribute__((aligned(16))) __bf16 Vs[128][72];
    const int b = blockIdx.x, hkv = b >> 5, kt = b & 31;
    const int tid = threadIdx.x;
    const float* Ks   = K + ((size_t)hkv * S + kt * 64) * D;
    const float* Vsrc = V + ((size_t)hkv * S + kt * 64) * D;
    char* Kimg = KbI + (size_t)(hkv * 32 + kt) * TILE_BYTES;
    char* Vimg = VtI + (size_t)(hkv * 32 + kt) * TILE_BYTES;

    #pragma unroll
    for (int i = 0; i < 4; ++i) {
        int idx = tid + i * 256;
        int r = idx >> 4, sl = idx & 15;
        float4 a = *reinterpret_cast<const float4*>(Ks + r * D + sl * 8);
        float4 c = *reinterpret_cast<const float4*>(Ks + r * D + sl * 8 + 4);
        bf16x8 f = {(__bf16)a.x, (__bf16)a.y, (__bf16)a.z, (__bf16)a.w,
                    (__bf16)c.x, (__bf16)c.y, (__bf16)c.z, (__bf16)c.w};
        *reinterpret_cast<bf16x8*>(Kimg + r * 256 + ((sl * 16) ^ ((r & 7) << 4))) = f;
    }
    #pragma unroll
    for (int i = 0; i < 8; ++i) {
        int idx = tid + i * 256;
        int r = idx >> 5, c = (idx & 31) * 4;
        float4 vv = *reinterpret_cast<const float4*>(Vsrc + r * D + c);
        Vs[c + 0][r] = (__bf16)vv.x; Vs[c + 1][r] = (__bf16)vv.y;
        Vs[c + 2][r] = (__bf16)vv.z; Vs[c + 3][r] = (__bf16)vv.w;
    }
    __syncthreads();
    #pragma unroll
    for (int i = 0; i < 4; ++i) {
        int idx = tid + i * 256;
        int d = idx >> 3, sl = idx & 7;
        bf16x8 v = *reinterpret_cast<const bf16x8*>(&Vs[d][sl * 8]);
        *reinterpret_cast<bf16x8*>(Vimg + d * 128 + ((sl * 16) ^ ((d & 7) << 4))) = v;
    }
}

// ------- main: 4-wave blocks, one 64-row q-tile, single-buffer LDS, 4 blocks/CU -------
__global__ __launch_bounds__(256, 4)
void attn_fused4(const float* __restrict__ Q, const char* __restrict__ KbI,
                 const char* __restrict__ VtI, float* __restrict__ out)
{
    __shared__ __attribute__((aligned(16))) char LDS_K[TILE_BYTES];   // 16 KB
    __shared__ __attribute__((aligned(16))) char LDS_V[TILE_BYTES];   // 16 KB
    __shared__ __attribute__((aligned(16))) char LDS_P[4][2048];      // 8 KB  -> 40 KB total

    const int bid = blockIdx.x;
    const int j   = bid >> 5;
    // per-CU resident set -> qt {16+x, 15-x, 31-x, x}: balanced iteration totals
    const int qt = (j < 8) ? (16 + j) : (j < 16) ? (23 - j) : (j < 24) ? (47 - j) : (j - 24);
    const int b5 = bid & 31;
    const int h  = (b5 & 7) * 4 + (b5 >> 3);   // hkv == bid%8 == XCD id (L2 locality)
    const int hkv = h >> 2;
    const int q0  = qt << 6;
    const int tid = threadIdx.x, wave = tid >> 6, lane = tid & 63;
    const int lo = lane & 15, hi = lane >> 4;
    const int qw0 = q0 + wave * 16;
    const bool winw = (qt >= 16);

    const char* Ktiles = KbI + (size_t)hkv * 32 * TILE_BYTES;
    const char* Vtiles = VtI + (size_t)hkv * 32 * TILE_BYTES;
    const float* Qh = Q + (size_t)h * S * D;

    // Q fragments (pre-scaled)
    bf16x8 qf[4];
    {
        const float* qs = Qh + (size_t)(qw0 + lo) * D + hi * 8;
        #pragma unroll
        for (int dc = 0; dc < 4; ++dc) {
            float4 a = *reinterpret_cast<const float4*>(qs + dc * 32);
            float4 b = *reinterpret_cast<const float4*>(qs + dc * 32 + 4);
            bf16x8 f;
            f[0] = (__bf16)(a.x * SCALE_L2E); f[1] = (__bf16)(a.y * SCALE_L2E);
            f[2] = (__bf16)(a.z * SCALE_L2E); f[3] = (__bf16)(a.w * SCALE_L2E);
            f[4] = (__bf16)(b.x * SCALE_L2E); f[5] = (__bf16)(b.y * SCALE_L2E);
            f[6] = (__bf16)(b.z * SCALE_L2E); f[7] = (__bf16)(b.w * SCALE_L2E);
            qf[dc] = f;
        }
    }

    // ================= phase A: row sums =================
    float lsum[4] = {0.f, 0.f, 0.f, 0.f};
    for (int kt = 0; kt <= qt; ++kt) {
        const char* src = Ktiles + (size_t)kt * TILE_BYTES;
        #pragma unroll
        for (int i = 0; i < 4; ++i)
            gl_lds16(src + (wave * 4 + i) * 1024 + lane * 16,
                     LDS_K + (wave * 4 + i) * 1024);
        __builtin_amdgcn_sched_barrier(0);
        asm volatile("s_waitcnt vmcnt(0)" ::: "memory");
        __builtin_amdgcn_s_barrier();
        __builtin_amdgcn_sched_barrier(0);
        #pragma unroll
        for (int cg = 0; cg < 4; ++cg) {
            f32x4 acc = {0.f, 0.f, 0.f, 0.f};
            const int row = cg * 16 + lo, swzr = (row & 7) << 4;
            #pragma unroll
            for (int dc = 0; dc < 4; ++dc) {
                bf16x8 kf = *reinterpret_cast<const bf16x8*>(
                    LDS_K + row * 256 + ((hi * 16 + dc * 64) ^ swzr));
                acc = __builtin_amdgcn_mfma_f32_16x16x32_bf16(qf[dc], kf, acc, 0, 0, 0);
            }
            const int k = (kt << 6) + cg * 16 + lo;
            #pragma unroll
            for (int r = 0; r < 4; ++r) {
                int q = qw0 + hi * 4 + r;
                lsum[r] += (k <= q) ? exp2f(acc[r]) : 0.f;
            }
        }
        // drain this wave's LDS reads before signaling (raw s_barrier skips lgkm)
        __builtin_amdgcn_sched_barrier(0);
        asm volatile("s_waitcnt lgkmcnt(0)" ::: "memory");
        __builtin_amdgcn_s_barrier();
        __builtin_amdgcn_sched_barrier(0);
    }
    float rcp_[4];
    #pragma unroll
    for (int r = 0; r < 4; ++r) {
        float v = lsum[r];
        v += __shfl_xor(v, 1); v += __shfl_xor(v, 2);
        v += __shfl_xor(v, 4); v += __shfl_xor(v, 8);
        rcp_[r] = 1.0f / v;
    }

    // ================= phase B =================
    f32x4 oacc[8];
    #pragma unroll
    for (int i = 0; i < 8; ++i) oacc[i] = (f32x4){0.f, 0.f, 0.f, 0.f};
    char* Ps = LDS_P[wave];

    for (int kt = 0; kt <= qt; ++kt) {
        const char* sk = Ktiles + (size_t)kt * TILE_BYTES;
        const char* sv = Vtiles + (size_t)kt * TILE_BYTES;
        #pragma unroll
        for (int i = 0; i < 4; ++i) {
            gl_lds16(sk + (wave * 4 + i) * 1024 + lane * 16, LDS_K + (wave * 4 + i) * 1024);
            gl_lds16(sv + (wave * 4 + i) * 1024 + lane * 16, LDS_V + (wave * 4 + i) * 1024);
        }
        __builtin_amdgcn_sched_barrier(0);
        asm volatile("s_waitcnt vmcnt(0)" ::: "memory");
        __builtin_amdgcn_s_barrier();
        __builtin_amdgcn_sched_barrier(0);

        const int kbase = kt << 6;

        // QK^T -> p -> per-wave P strip (bf16)
        #pragma unroll
        for (int cg = 0; cg < 4; ++cg) {
            f32x4 acc = {0.f, 0.f, 0.f, 0.f};
            const int row = cg * 16 + lo, swzr = (row & 7) << 4;
            #pragma unroll
            for (int dc = 0; dc < 4; ++dc) {
                bf16x8 kf = *reinterpret_cast<const bf16x8*>(
                    LDS_K + row * 256 + ((hi * 16 + dc * 64) ^ swzr));
                acc = __builtin_amdgcn_mfma_f32_16x16x32_bf16(qf[dc], kf, acc, 0, 0, 0);
            }
            const int k = kbase + cg * 16 + lo;
            #pragma unroll
            for (int r = 0; r < 4; ++r) {
                const int q = qw0 + hi * 4 + r;
                float pv = (k <= q) ? exp2f(acc[r]) * rcp_[r] : 0.f;
                const int prow = hi * 4 + r;
                *reinterpret_cast<__bf16*>(
                    Ps + prow * 128 + ((2 * (cg * 16 + lo)) ^ ((prow & 7) << 4))) = (__bf16)pv;
            }
        }

        // wide P (+window) stores from strip readback
        {
            const int row = lane >> 2;
            const int q = qw0 + row;
            float* dstP = out + O1 + ((size_t)h * S + q) * S + kbase;
            #pragma unroll
            for (int t = 0; t < 2; ++t) {
                int boff = (((lane & 3) * 16 + t * 64) ^ ((row & 7) << 4));
                bf16x8 pv8 = *reinterpret_cast<const bf16x8*>(Ps + row * 128 + boff);
                f32x4 f0 = {(float)pv8[0], (float)pv8[1], (float)pv8[2], (float)pv8[3]};
                f32x4 f1 = {(float)pv8[4], (float)pv8[5], (float)pv8[6], (float)pv8[7]};
                int k0 = (lane & 3) * 8 + t * 32;
                st4(dstP + k0, f0);
                st4(dstP + k0 + 4, f1);
                if (winw) {
                    float* dstW = out + O2 + ((size_t)h * W + (q - W)) * S + kbase;
                    st4(dstW + k0, f0);
                    st4(dstW + k0 + 4, f1);
                }
            }
        }

        // PV accumulate
        #pragma unroll
        for (int kc = 0; kc < 2; ++kc) {
            const int cb = (kc * 64 + hi * 16) ^ ((lo & 7) << 4);
            bf16x8 pf = *reinterpret_cast<const bf16x8*>(Ps + lo * 128 + cb);
            #pragma unroll
            for (int dg = 0; dg < 8; ++dg) {
                bf16x8 vf = *reinterpret_cast<const bf16x8*>(LDS_V + (dg * 16 + lo) * 128 + cb);
                oacc[dg] = __builtin_amdgcn_mfma_f32_16x16x32_bf16(pf, vf, oacc[dg], 0, 0, 0);
            }
        }

        // drain this wave's LDS ops before signaling
        __builtin_amdgcn_sched_barrier(0);
        asm volatile("s_waitcnt lgkmcnt(0)" ::: "memory");
        __builtin_amdgcn_s_barrier();
        __builtin_amdgcn_sched_barrier(0);
    }

    // zero-fill masked tiles
    {
        const int zr = lane >> 2;
        const int c0 = (lane & 3) * 16;
        const f32x4 z = {0.f, 0.f, 0.f, 0.f};
        const int q = qw0 + zr;
        for (int kt = qt + 1; kt < 32; ++kt) {
            float* dp = out + O1 + ((size_t)h * S + q) * S + kt * 64 + c0;
            #pragma unroll
            for (int jj = 0; jj < 4; ++jj) st4(dp + jj * 4, z);
            if (winw) {
                float* dw = out + O2 + ((size_t)h * W + (q - W)) * S + kt * 64 + c0;
                #pragma unroll
                for (int jj = 0; jj < 4; ++jj) st4(dw + jj * 4, z);
            }
        }
    }

    // attn_output (S, HQ, D)
    #pragma unroll
    for (int dg = 0; dg < 8; ++dg) {
        #pragma unroll
        for (int r = 0; r < 4; ++r) {
            const int q = qw0 + hi * 4 + r;
            out[((size_t)q * HQ + h) * D + dg * 16 + lo] = oacc[dg][r];
        }
    }
}

extern "C" void kernel_launch(void* const* d_in, const int* in_sizes, int n_in,
                              void* d_out, int out_size, void* d_ws, size_t ws_size,
                              hipStream_t stream)
{
    const float* Q = (const float*)d_in[0];
    const float* K = (const float*)d_in[1];
    const float* V = (const float*)d_in[2];
    float* out = (float*)d_out;

    char* KbI = (char*)d_ws;                                   // 4 MB tile images
    char* VtI = (char*)d_ws + (size_t)4 * 1024 * 1024;         // 4 MB tile images

    hipLaunchKernelGGL(prep_kernel, dim3(256),  dim3(256), 0, stream, K, V, KbI, VtI);
    hipLaunchKernelGGL(attn_fused4, dim3(1024), dim3(256), 0, stream, Q, KbI, VtI, out);
}

// Round 9
// 276.973 us; speedup vs baseline: 2.9286x; 1.0854x over previous
//
#include <hip/hip_runtime.h>
#include <hip/hip_bf16.h>

typedef __bf16 bf16x8 __attribute__((ext_vector_type(8)));
typedef float f32x4 __attribute__((ext_vector_type(4)));
static_assert(sizeof(bf16x8) == 16, "bf16x8 must be 16B");

constexpr int S = 2048, D = 128, HQ = 32, W = 1024;
constexpr float SCALE_L2E = 0.08838834764831845f * 1.4426950408889634f;

constexpr size_t O1 = (size_t)S * HQ * D;        // attn_weights offset
constexpr size_t O2 = O1 + (size_t)HQ * S * S;   // window offset
constexpr int TILE64 = 64 * 256;                 // 16 KB (64-row K image)
constexpr int TILE32 = 32 * 256;                 // 8 KB  (32-row K / 32-col V image)

__device__ __forceinline__ void gl_lds16(const void* g, void* l) {
    __builtin_amdgcn_global_load_lds(
        (const __attribute__((address_space(1))) void*)(unsigned long long)g,
        (__attribute__((address_space(3))) void*)(unsigned int)(unsigned long long)l,
        16, 0, 0);
}
__device__ __forceinline__ void st4(float* p, f32x4 v) {
    *reinterpret_cast<f32x4*>(p) = v;
}

// ---------------- prep: K,V -> bf16 pre-swizzled tile images in ws ----------------
// K: 64-row blocks, row r: byte = r*256 + (sl*16 ^ ((r&7)<<4))  [= two stacked 32-row images]
// V: per-32-col images: [d 0..127] x 64B, byte = d*64 + (sl*16 ^ ((d&3)<<4)), sl=0..3
__global__ __launch_bounds__(256)
void prep_kernel(const float* __restrict__ K, const float* __restrict__ V,
                 char* __restrict__ KbI, char* __restrict__ VtI)
{
    __shared__ __attribute__((aligned(16))) __bf16 Vs[128][72];
    const int b = blockIdx.x, hkv = b >> 5, kt = b & 31;
    const int tid = threadIdx.x;
    const float* Ks   = K + ((size_t)hkv * S + kt * 64) * D;
    const float* Vsrc = V + ((size_t)hkv * S + kt * 64) * D;
    char* Kimg = KbI + (size_t)(hkv * 32 + kt) * TILE64;
    char* Vimg = VtI + (size_t)(hkv * 32 + kt) * TILE64;

    #pragma unroll
    for (int i = 0; i < 4; ++i) {
        int idx = tid + i * 256;
        int r = idx >> 4, sl = idx & 15;
        float4 a = *reinterpret_cast<const float4*>(Ks + r * D + sl * 8);
        float4 c = *reinterpret_cast<const float4*>(Ks + r * D + sl * 8 + 4);
        bf16x8 f = {(__bf16)a.x, (__bf16)a.y, (__bf16)a.z, (__bf16)a.w,
                    (__bf16)c.x, (__bf16)c.y, (__bf16)c.z, (__bf16)c.w};
        *reinterpret_cast<bf16x8*>(Kimg + r * 256 + ((sl * 16) ^ ((r & 7) << 4))) = f;
    }
    #pragma unroll
    for (int i = 0; i < 8; ++i) {
        int idx = tid + i * 256;
        int r = idx >> 5, c = (idx & 31) * 4;
        float4 vv = *reinterpret_cast<const float4*>(Vsrc + r * D + c);
        Vs[c + 0][r] = (__bf16)vv.x; Vs[c + 1][r] = (__bf16)vv.y;
        Vs[c + 2][r] = (__bf16)vv.z; Vs[c + 3][r] = (__bf16)vv.w;
    }
    __syncthreads();
    #pragma unroll
    for (int i = 0; i < 4; ++i) {
        int idx = tid + i * 256;            // 0..1023 = 2 images x 512 chunks
        int img = idx >> 9;
        int rem = idx & 511;
        int d = rem >> 2, sl = rem & 3;
        bf16x8 v = *reinterpret_cast<const bf16x8*>(&Vs[d][img * 32 + sl * 8]);
        *reinterpret_cast<bf16x8*>(Vimg + img * TILE32 + d * 64 + ((sl * 16) ^ ((d & 3) << 4))) = v;
    }
}

// ------- main: 4-wave blocks, KVBLK=32 double-buffered, counted vmcnt, 4 blocks/CU -------
__global__ __launch_bounds__(256, 4)
void attn_fused5(const float* __restrict__ Q, const char* __restrict__ KbI,
                 const char* __restrict__ VtI, float* __restrict__ out)
{
    __shared__ __attribute__((aligned(16))) char BUF[4][TILE32];   // 32 KB
    __shared__ __attribute__((aligned(16))) char PST[4][1024];     // 4 KB -> 36 KB total

    const int bid = blockIdx.x;
    const int j   = bid >> 5;
    // per-CU resident set -> qt {16+x, 15-x, 31-x, x}: balanced iteration totals
    const int qt = (j < 8) ? (16 + j) : (j < 16) ? (23 - j) : (j < 24) ? (47 - j) : (j - 24);
    const int b5 = bid & 31;
    const int h  = (b5 & 7) * 4 + (b5 >> 3);   // hkv == bid%8 == XCD id (L2 locality)
    const int hkv = h >> 2;
    const int q0  = qt << 6;
    const int tid = threadIdx.x, wave = tid >> 6, lane = tid & 63;
    const int lo = lane & 15, hi = lane >> 4;
    const int qw0 = q0 + wave * 16;
    const bool winw = (qt >= 16);

    const char* Ktiles = KbI + (size_t)hkv * 32 * TILE64;
    const char* Vtiles = VtI + (size_t)hkv * 32 * TILE64;
    const float* Qh = Q + (size_t)h * S * D;

    // Q fragments (pre-scaled)
    bf16x8 qf[4];
    {
        const float* qs = Qh + (size_t)(qw0 + lo) * D + hi * 8;
        #pragma unroll
        for (int dc = 0; dc < 4; ++dc) {
            float4 a = *reinterpret_cast<const float4*>(qs + dc * 32);
            float4 b = *reinterpret_cast<const float4*>(qs + dc * 32 + 4);
            bf16x8 f;
            f[0] = (__bf16)(a.x * SCALE_L2E); f[1] = (__bf16)(a.y * SCALE_L2E);
            f[2] = (__bf16)(a.z * SCALE_L2E); f[3] = (__bf16)(a.w * SCALE_L2E);
            f[4] = (__bf16)(b.x * SCALE_L2E); f[5] = (__bf16)(b.y * SCALE_L2E);
            f[6] = (__bf16)(b.z * SCALE_L2E); f[7] = (__bf16)(b.w * SCALE_L2E);
            qf[dc] = f;
        }
    }

    // ====== phase A: row sums, KVBLK=64, K double-buffered in BUF[0..1]/BUF[2..3] ======
    float lsum[4] = {0.f, 0.f, 0.f, 0.f};
    {
        #pragma unroll
        for (int i = 0; i < 4; ++i)
            gl_lds16(Ktiles + (wave * 4 + i) * 1024 + lane * 16,
                     &BUF[0][0] + (wave * 4 + i) * 1024);
        __builtin_amdgcn_sched_barrier(0);
        asm volatile("s_waitcnt vmcnt(0)" ::: "memory");
        __builtin_amdgcn_s_barrier();
        __builtin_amdgcn_sched_barrier(0);

        int cur = 0;
        for (int kt = 0; kt <= qt; ++kt) {
            if (kt < qt) {
                const char* src = Ktiles + (size_t)(kt + 1) * TILE64;
                char* dst = &BUF[(cur ^ 1) * 2][0];
                #pragma unroll
                for (int i = 0; i < 4; ++i)
                    gl_lds16(src + (wave * 4 + i) * 1024 + lane * 16, dst + (wave * 4 + i) * 1024);
                __builtin_amdgcn_sched_barrier(0);
            }
            const char* KtB = &BUF[cur * 2][0];
            #pragma unroll
            for (int cg = 0; cg < 4; ++cg) {
                f32x4 acc = {0.f, 0.f, 0.f, 0.f};
                const int row = cg * 16 + lo, swzr = (row & 7) << 4;
                #pragma unroll
                for (int dc = 0; dc < 4; ++dc) {
                    bf16x8 kf = *reinterpret_cast<const bf16x8*>(
                        KtB + row * 256 + ((hi * 16 + dc * 64) ^ swzr));
                    acc = __builtin_amdgcn_mfma_f32_16x16x32_bf16(qf[dc], kf, acc, 0, 0, 0);
                }
                const int k = (kt << 6) + cg * 16 + lo;
                #pragma unroll
                for (int r = 0; r < 4; ++r) {
                    int q = qw0 + hi * 4 + r;
                    lsum[r] += (k <= q) ? exp2f(acc[r]) : 0.f;
                }
            }
            __builtin_amdgcn_sched_barrier(0);
            asm volatile("s_waitcnt vmcnt(0) lgkmcnt(0)" ::: "memory");
            __builtin_amdgcn_s_barrier();
            __builtin_amdgcn_sched_barrier(0);
            cur ^= 1;
        }
    }
    float rcp_[4];
    #pragma unroll
    for (int r = 0; r < 4; ++r) {
        float v = lsum[r];
        v += __shfl_xor(v, 1); v += __shfl_xor(v, 2);
        v += __shfl_xor(v, 4); v += __shfl_xor(v, 8);
        rcp_[r] = 1.0f / v;
    }

    // ====== phase B: KVBLK=32, K db = BUF[0/1], V db = BUF[2/3], counted vmcnt ======
    f32x4 oacc[8];
    #pragma unroll
    for (int i = 0; i < 8; ++i) oacc[i] = (f32x4){0.f, 0.f, 0.f, 0.f};
    char* Ps = PST[wave];
    const int nk32 = (qt + 1) * 2;

    {
        #pragma unroll
        for (int i = 0; i < 2; ++i) {
            gl_lds16(Ktiles + (wave * 2 + i) * 1024 + lane * 16, &BUF[0][0] + (wave * 2 + i) * 1024);
            gl_lds16(Vtiles + (wave * 2 + i) * 1024 + lane * 16, &BUF[2][0] + (wave * 2 + i) * 1024);
        }
        __builtin_amdgcn_sched_barrier(0);
        asm volatile("s_waitcnt vmcnt(0)" ::: "memory");
        __builtin_amdgcn_s_barrier();
        __builtin_amdgcn_sched_barrier(0);
    }

    int cur = 0;
    for (int t = 0; t < nk32; ++t) {
        const bool more = (t + 1 < nk32);
        if (more) {
            const char* sk = Ktiles + (size_t)(t + 1) * TILE32;
            const char* sv = Vtiles + (size_t)(t + 1) * TILE32;
            char* dk = &BUF[cur ^ 1][0];
            char* dv = &BUF[2 + (cur ^ 1)][0];
            #pragma unroll
            for (int i = 0; i < 2; ++i) {
                gl_lds16(sk + (wave * 2 + i) * 1024 + lane * 16, dk + (wave * 2 + i) * 1024);
                gl_lds16(sv + (wave * 2 + i) * 1024 + lane * 16, dv + (wave * 2 + i) * 1024);
            }
            __builtin_amdgcn_sched_barrier(0);
        }
        const char* KtB = &BUF[cur][0];
        const char* VtB = &BUF[2 + cur][0];
        const int kbase = t * 32;

        // QK^T (32 k-cols) -> p -> per-wave P strip (bf16, 64B rows, (row&3)<<4 XOR)
        #pragma unroll
        for (int cg = 0; cg < 2; ++cg) {
            f32x4 acc = {0.f, 0.f, 0.f, 0.f};
            const int row = cg * 16 + lo, swzr = (row & 7) << 4;
            #pragma unroll
            for (int dc = 0; dc < 4; ++dc) {
                bf16x8 kf = *reinterpret_cast<const bf16x8*>(
                    KtB + row * 256 + ((hi * 16 + dc * 64) ^ swzr));
                acc = __builtin_amdgcn_mfma_f32_16x16x32_bf16(qf[dc], kf, acc, 0, 0, 0);
            }
            const int k = kbase + cg * 16 + lo;
            #pragma unroll
            for (int r = 0; r < 4; ++r) {
                const int q = qw0 + hi * 4 + r;
                float pv = (k <= q) ? exp2f(acc[r]) * rcp_[r] : 0.f;
                const int prow = hi * 4 + r;
                *reinterpret_cast<__bf16*>(
                    Ps + prow * 64 + ((2 * (cg * 16 + lo)) ^ ((prow & 3) << 4))) = (__bf16)pv;
            }
        }

        // P (+window) stores: strip readback, 1 b128 read -> 2 float4 (x2 if window)
        {
            const int row = lane >> 2;        // 0..15 q-row
            const int sl  = lane & 3;         // 16B slot
            const int q = qw0 + row;
            bf16x8 pv8 = *reinterpret_cast<const bf16x8*>(
                Ps + row * 64 + ((sl * 16) ^ ((row & 3) << 4)));
            f32x4 f0 = {(float)pv8[0], (float)pv8[1], (float)pv8[2], (float)pv8[3]};
            f32x4 f1 = {(float)pv8[4], (float)pv8[5], (float)pv8[6], (float)pv8[7]};
            float* dstP = out + O1 + ((size_t)h * S + q) * S + kbase + sl * 8;
            st4(dstP, f0);
            st4(dstP + 4, f1);
            if (winw) {
                float* dstW = out + O2 + ((size_t)h * W + (q - W)) * S + kbase + sl * 8;
                st4(dstW, f0);
                st4(dstW + 4, f1);
            }
        }

        // PV accumulate: one MFMA per dg covers K=32
        {
            bf16x8 pf = *reinterpret_cast<const bf16x8*>(
                Ps + lo * 64 + ((hi * 16) ^ ((lo & 3) << 4)));
            #pragma unroll
            for (int dg = 0; dg < 8; ++dg) {
                const int d = dg * 16 + lo;
                bf16x8 vf = *reinterpret_cast<const bf16x8*>(
                    VtB + d * 64 + ((hi * 16) ^ ((d & 3) << 4)));
                oacc[dg] = __builtin_amdgcn_mfma_f32_16x16x32_bf16(pf, vf, oacc[dg], 0, 0, 0);
            }
        }

        if (more) {
            __builtin_amdgcn_sched_barrier(0);
            // outstanding: 4 loads (oldest this iter) + 2/4 stores (newest).
            // counted wait: loads landed, stores keep one iteration of slack.
            if (winw) asm volatile("s_waitcnt vmcnt(4) lgkmcnt(0)" ::: "memory");
            else      asm volatile("s_waitcnt vmcnt(2) lgkmcnt(0)" ::: "memory");
            __builtin_amdgcn_s_barrier();
            __builtin_amdgcn_sched_barrier(0);
        }
        cur ^= 1;
    }

    // zero-fill masked tiles
    {
        const int zr = lane >> 2;
        const int c0 = (lane & 3) * 16;
        const f32x4 z = {0.f, 0.f, 0.f, 0.f};
        const int q = qw0 + zr;
        for (int kt = qt + 1; kt < 32; ++kt) {
            float* dp = out + O1 + ((size_t)h * S + q) * S + kt * 64 + c0;
            #pragma unroll
            for (int jj = 0; jj < 4; ++jj) st4(dp + jj * 4, z);
            if (winw) {
                float* dw = out + O2 + ((size_t)h * W + (q - W)) * S + kt * 64 + c0;
                #pragma unroll
                for (int jj = 0; jj < 4; ++jj) st4(dw + jj * 4, z);
            }
        }
    }

    // attn_output (S, HQ, D)
    #pragma unroll
    for (int dg = 0; dg < 8; ++dg) {
        #pragma unroll
        for (int r = 0; r < 4; ++r) {
            const int q = qw0 + hi * 4 + r;
            out[((size_t)q * HQ + h) * D + dg * 16 + lo] = oacc[dg][r];
        }
    }
}

extern "C" void kernel_launch(void* const* d_in, const int* in_sizes, int n_in,
                              void* d_out, int out_size, void* d_ws, size_t ws_size,
                              hipStream_t stream)
{
    const float* Q = (const float*)d_in[0];
    const float* K = (const float*)d_in[1];
    const float* V = (const float*)d_in[2];
    float* out = (float*)d_out;

    char* KbI = (char*)d_ws;                                   // 4 MB tile images
    char* VtI = (char*)d_ws + (size_t)4 * 1024 * 1024;         // 4 MB tile images

    hipLaunchKernelGGL(prep_kernel, dim3(256),  dim3(256), 0, stream, K, V, KbI, VtI);
    hipLaunchKernelGGL(attn_fused5, dim3(1024), dim3(256), 0, stream, Q, KbI, VtI, out);
}